// Round 3
// baseline (311.787 us; speedup 1.0000x reference)
//
#include <hip/hip_runtime.h>

// DBASolver: B=16, N=196608, C=2.
// Pass 1: per-batch reduction of H_eff (21 sym) + g_eff (6), Schur term fused.
// Pass 2: 16x 6x6 Gauss-Jordan solves.
// Pass 3: per-point delta_depth = invHdd * (g_d - H_pd . dp_unclipped).
//
// R2 finding: J_p loaded AoS (96 B lane stride) caps the read path at
// ~2.5 TB/s (48 lines/instr vs 8). Fix: wave-private LDS staging with
// fully-coalesced 16B-lane-stride global loads (m13 pattern), SoA LDS
// layout lds[row][pair] (+1 col pad) -> conflict-free reads, no barriers.

constexpr int NACC = 27;  // 21 upper-triangular H entries + 6 g entries

__device__ __forceinline__ void accum_point(
    const float* __restrict__ ja, const float* __restrict__ jb,
    float r0, float r1, float conf, float nlam, float jd0, float jd1,
    float lam, float* __restrict__ A, float* __restrict__ g)
{
    float h[6], gp[6];
#pragma unroll
    for (int i = 0; i < 6; ++i) {
        h[i]  = conf * (ja[i] * jd0 + jb[i] * jd1);   // H_pd[b,n,i]
        gp[i] = conf * (ja[i] * r0 + jb[i] * r1);     // g_p contribution
    }
    const float hdd = conf * (jd0 * jd0 + jd1 * jd1);
    const float inv = 1.0f / fmaxf(hdd + lam + nlam, 1e-4f);
    const float gd  = conf * (jd0 * r0 + jd1 * r1);
    const float gdinv = gd * inv;
    int idx = 0;
#pragma unroll
    for (int i = 0; i < 6; ++i) {
        const float hii = h[i] * inv;
#pragma unroll
        for (int j = i; j < 6; ++j) {
            A[idx] += conf * (ja[i] * ja[j] + jb[i] * jb[j]) - hii * h[j];
            ++idx;
        }
        g[i] += gp[i] - h[i] * gdinv;
    }
}

// Stage this wave's 128-point J_p chunk (1536 floats) into wave-private LDS.
// Global: 6 x b128, lane stride 16 B (fully coalesced).
// LDS write bank = (4*s4+k+pair)%32 -> <=2-way. Read bank=(row+lane)%32 -> 2-way (free).
__device__ __forceinline__ void stage_jp(
    const float* __restrict__ J_p, size_t wp, int lane,
    float (*__restrict__ ldsw)[65])
{
    const float4* jp4 = (const float4*)(J_p + wp * 12);
#pragma unroll
    for (int q = 0; q < 6; ++q) {
        const int l4 = (q << 6) + lane;   // 0..383
        const float4 v = jp4[l4];
        const int pair = l4 / 6;
        const int s4 = l4 - 6 * pair;
        ldsw[4 * s4 + 0][pair] = v.x;
        ldsw[4 * s4 + 1][pair] = v.y;
        ldsw[4 * s4 + 2][pair] = v.z;
        ldsw[4 * s4 + 3][pair] = v.w;
    }
}

__global__ __launch_bounds__(256) void dba_reduce(
    const float* __restrict__ r, const float* __restrict__ w,
    const float* __restrict__ J_p, const float* __restrict__ J_d,
    const float* __restrict__ lmbda, float* __restrict__ acc, int N)
{
    __shared__ float lds[4][24][65];   // wave-private SoA J_p tiles, ~25 KB
    __shared__ float sred[4][NACC];
    const int b = blockIdx.y;
    const float lam = lmbda[b];
    const int wave = threadIdx.x >> 6;
    const int lane = threadIdx.x & 63;

    float A[21], g[6];
#pragma unroll
    for (int i = 0; i < 21; ++i) A[i] = 0.f;
#pragma unroll
    for (int i = 0; i < 6; ++i) g[i] = 0.f;

    const size_t base = (size_t)b * (size_t)N;
    const int tiles = N >> 9;  // 512 points per block-tile
    for (int tile = blockIdx.x; tile < tiles; tile += gridDim.x) {
        const size_t wp = base + ((size_t)tile << 9) + (wave << 7);  // wave's 128 pts
        stage_jp(J_p, wp, lane, lds[wave]);

        const size_t p = wp + (lane << 1);  // this thread's point pair
        const float4 rv = *(const float4*)(r + p * 2);
        const float4 wv = *(const float4*)(w + p * 2);
        const float4 jd = *(const float4*)(J_d + p * 2);

        float f0[12], f1[12];
#pragma unroll
        for (int i = 0; i < 12; ++i) f0[i] = lds[wave][i][lane];
#pragma unroll
        for (int i = 0; i < 12; ++i) f1[i] = lds[wave][12 + i][lane];

        accum_point(f0, f0 + 6, rv.x, rv.y, wv.x, wv.y, jd.x, jd.y, lam, A, g);
        accum_point(f1, f1 + 6, rv.z, rv.w, wv.z, wv.w, jd.z, jd.w, lam, A, g);
    }

    float v[NACC];
#pragma unroll
    for (int i = 0; i < 21; ++i) v[i] = A[i];
#pragma unroll
    for (int i = 0; i < 6; ++i) v[21 + i] = g[i];
#pragma unroll
    for (int off = 32; off > 0; off >>= 1) {
#pragma unroll
        for (int i = 0; i < NACC; ++i) v[i] += __shfl_down(v[i], off, 64);
    }
    if (lane == 0) {
#pragma unroll
        for (int i = 0; i < NACC; ++i) sred[wave][i] = v[i];
    }
    __syncthreads();
    if (threadIdx.x < NACC) {
        const float s = sred[0][threadIdx.x] + sred[1][threadIdx.x] +
                        sred[2][threadIdx.x] + sred[3][threadIdx.x];
        atomicAdd(&acc[b * 32 + threadIdx.x], s);
    }
}

__global__ void dba_solve(const float* __restrict__ acc,
                          const float* __restrict__ lmbda,
                          float* __restrict__ pose_out,
                          float* __restrict__ dp_ws, int B)
{
    const int b = blockIdx.x * blockDim.x + threadIdx.x;
    if (b >= B) return;
    float M[6][7];
    const float* a = acc + b * 32;
    int idx = 0;
#pragma unroll
    for (int i = 0; i < 6; ++i) {
#pragma unroll
        for (int j = i; j < 6; ++j) {
            const float t = a[idx++];
            M[i][j] = t;
            M[j][i] = t;
        }
    }
#pragma unroll
    for (int i = 0; i < 6; ++i) M[i][6] = a[21 + i];
    const float lam = lmbda[b];
#pragma unroll
    for (int i = 0; i < 6; ++i) M[i][i] += lam + 0.011f;

    // Gauss-Jordan, no pivoting (matrix strongly diagonally dominant SPD)
#pragma unroll
    for (int k = 0; k < 6; ++k) {
        const float piv = 1.0f / M[k][k];
#pragma unroll
        for (int j = 0; j < 7; ++j) M[k][j] *= piv;
#pragma unroll
        for (int i = 0; i < 6; ++i) {
            if (i == k) continue;
            const float f = M[i][k];
#pragma unroll
            for (int j = 0; j < 7; ++j) M[i][j] -= f * M[k][j];
        }
    }
#pragma unroll
    for (int i = 0; i < 6; ++i) {
        const float x = M[i][6];
        dp_ws[b * 6 + i] = x;                 // UNCLIPPED dp feeds pass 3
        pose_out[b * 6 + i] = fminf(fmaxf(x, -2.0f), 2.0f);
    }
}

__global__ __launch_bounds__(256) void dba_depth(
    const float* __restrict__ r, const float* __restrict__ w,
    const float* __restrict__ J_p, const float* __restrict__ J_d,
    const float* __restrict__ lmbda, const float* __restrict__ dp_ws,
    float* __restrict__ depth_out, int N)
{
    __shared__ float lds[4][24][65];
    const int b = blockIdx.y;
    const float lam = lmbda[b];
    float dp[6];
#pragma unroll
    for (int i = 0; i < 6; ++i) dp[i] = dp_ws[b * 6 + i];

    const int wave = threadIdx.x >> 6;
    const int lane = threadIdx.x & 63;
    const size_t base = (size_t)b * (size_t)N;
    const int tiles = N >> 9;
    for (int tile = blockIdx.x; tile < tiles; tile += gridDim.x) {
        const size_t wp = base + ((size_t)tile << 9) + (wave << 7);
        stage_jp(J_p, wp, lane, lds[wave]);

        const size_t p = wp + (lane << 1);
        const float4 rv = *(const float4*)(r + p * 2);
        const float4 wv = *(const float4*)(w + p * 2);
        const float4 jd = *(const float4*)(J_d + p * 2);

        float f0[12], f1[12];
#pragma unroll
        for (int i = 0; i < 12; ++i) f0[i] = lds[wave][i][lane];
#pragma unroll
        for (int i = 0; i < 12; ++i) f1[i] = lds[wave][12 + i][lane];

        float2 outv;
        {
            float v = 0.f;
#pragma unroll
            for (int i = 0; i < 6; ++i)
                v += (f0[i] * jd.x + f0[6 + i] * jd.y) * dp[i];
            v *= wv.x;
            const float hdd = wv.x * (jd.x * jd.x + jd.y * jd.y);
            const float inv = 1.0f / fmaxf(hdd + lam + wv.y, 1e-4f);
            const float gd  = wv.x * (jd.x * rv.x + jd.y * rv.y);
            outv.x = inv * (gd - v);
        }
        {
            float v = 0.f;
#pragma unroll
            for (int i = 0; i < 6; ++i)
                v += (f1[i] * jd.z + f1[6 + i] * jd.w) * dp[i];
            v *= wv.z;
            const float hdd = wv.z * (jd.z * jd.z + jd.w * jd.w);
            const float inv = 1.0f / fmaxf(hdd + lam + wv.w, 1e-4f);
            const float gd  = wv.z * (jd.z * rv.z + jd.w * rv.w);
            outv.y = inv * (gd - v);
        }
        *(float2*)(depth_out + p) = outv;
    }
}

extern "C" void kernel_launch(void* const* d_in, const int* in_sizes, int n_in,
                              void* d_out, int out_size, void* d_ws, size_t ws_size,
                              hipStream_t stream)
{
    const float* r   = (const float*)d_in[0];
    const float* w   = (const float*)d_in[1];
    const float* J_p = (const float*)d_in[2];
    const float* J_d = (const float*)d_in[3];
    const float* lmb = (const float*)d_in[4];
    const int B = in_sizes[4];            // 16
    const int N = in_sizes[0] / (B * 2);  // 196608

    float* acc   = (float*)d_ws;           // B*32 accumulators
    float* dp_ws = (float*)d_ws + B * 32;  // B*6 unclipped dp
    float* out   = (float*)d_out;

    hipMemsetAsync(acc, 0, B * 32 * sizeof(float), stream);

    // 96 blocks/batch x 16 = 1536 blocks = 6/CU (LDS-limited), 4 tiles/block
    dim3 grid(96, B);
    dba_reduce<<<grid, 256, 0, stream>>>(r, w, J_p, J_d, lmb, acc, N);
    dba_solve<<<1, 64, 0, stream>>>(acc, lmb, out, dp_ws, B);
    dba_depth<<<grid, 256, 0, stream>>>(r, w, J_p, J_d, lmb, dp_ws, out + B * 6, N);
}